// Round 1
// baseline (2174.798 us; speedup 1.0000x reference)
//
#include <hip/hip_runtime.h>
#include <hip/hip_bf16.h>

#define N_NODES 50000
#define N_EDGES 800000
#define D_FEAT  64

// ---------------- kernels ----------------

__global__ void deg_kernel(const int* __restrict__ src, float* __restrict__ deg, int nE) {
    int e = blockIdx.x * blockDim.x + threadIdx.x;
    if (e < nE) atomicAdd(&deg[src[e]], 1.0f);
}

__global__ void dinv_kernel(float* __restrict__ deg, int n) {
    int i = blockIdx.x * blockDim.x + threadIdx.x;
    if (i < n) {
        float d = deg[i];
        deg[i] = (d > 0.0f) ? rsqrtf(d) : 0.0f;
    }
}

__global__ void w_kernel(const int* __restrict__ src, const int* __restrict__ dst,
                         const float* __restrict__ dinv, float* __restrict__ w, int nE) {
    int e = blockIdx.x * blockDim.x + threadIdx.x;
    if (e < nE) w[e] = dinv[src[e]] * dinv[dst[e]];
}

// scatter SpMM: y[dst[e], :] += w[e] * x[src[e], :]
// 16 threads per edge, each handles 4 consecutive floats (float4 gather).
__global__ void spmm_scatter_kernel(const int* __restrict__ src, const int* __restrict__ dst,
                                    const float* __restrict__ w,
                                    const float* __restrict__ x, float* __restrict__ y,
                                    int nE) {
    int t = blockIdx.x * blockDim.x + threadIdx.x;
    int e = t >> 4;
    if (e >= nE) return;
    int c = (t & 15) << 2;          // feature offset: 0,4,...,60
    float we = w[e];
    const float4 xv = *(const float4*)(x + (long)src[e] * D_FEAT + c);
    float* yp = y + (long)dst[e] * D_FEAT + c;
    atomicAdd(yp + 0, we * xv.x);
    atomicAdd(yp + 1, we * xv.y);
    atomicAdd(yp + 2, we * xv.z);
    atomicAdd(yp + 3, we * xv.w);
}

// h = a * x   (float4)
__global__ void scale_kernel(const float* __restrict__ x, float* __restrict__ h,
                             float a, int n4) {
    int i = blockIdx.x * blockDim.x + threadIdx.x;
    if (i < n4) {
        float4 v = ((const float4*)x)[i];
        float4 r; r.x = a * v.x; r.y = a * v.y; r.z = a * v.z; r.w = a * v.w;
        ((float4*)h)[i] = r;
    }
}

// h += a * x  (float4)
__global__ void axpy_kernel(const float* __restrict__ x, float* __restrict__ h,
                            float a, int n4) {
    int i = blockIdx.x * blockDim.x + threadIdx.x;
    if (i < n4) {
        float4 v = ((const float4*)x)[i];
        float4 o = ((float4*)h)[i];
        o.x += a * v.x; o.y += a * v.y; o.z += a * v.z; o.w += a * v.w;
        ((float4*)h)[i] = o;
    }
}

// ---------------- launch ----------------

extern "C" void kernel_launch(void* const* d_in, const int* in_sizes, int n_in,
                              void* d_out, int out_size, void* d_ws, size_t ws_size,
                              hipStream_t stream) {
    const float* feat = (const float*)d_in[0];
    const int*   src  = (const int*)d_in[1];
    const int*   dst  = (const int*)d_in[2];
    float* h = (float*)d_out;

    float* ws = (float*)d_ws;
    // layout (floats): deg[50000] | w[800000] | bufA[3.2M] | bufB[3.2M]
    float* deg  = ws;                       // 50000
    float* w    = ws + 50048;               // 800000 (16B-aligned offset)
    float* bufA = ws + 850048;              // 3,200,000
    float* bufB = ws + 4050048;             // 3,200,000

    const int nE = N_EDGES;
    const int nN = N_NODES;
    const int nElem = N_NODES * D_FEAT;     // 3,200,000
    const int n4 = nElem / 4;               // 800,000

    const int B = 256;
    dim3 blk(B);

    // 1. degree
    hipMemsetAsync(deg, 0, (size_t)nN * sizeof(float), stream);
    deg_kernel<<<(nE + B - 1) / B, blk, 0, stream>>>(src, deg, nE);
    // 2. deg -> d^{-1/2} in place
    dinv_kernel<<<(nN + B - 1) / B, blk, 0, stream>>>(deg, nN);
    // 3. edge weights
    w_kernel<<<(nE + B - 1) / B, blk, 0, stream>>>(src, dst, deg, w, nE);

    const int spmmThreads = nE * 16;
    const int spmmGrid = (spmmThreads + B - 1) / B;

    // 4. x1 = A @ feat ; h = 0.8 * x1
    hipMemsetAsync(bufA, 0, (size_t)nElem * sizeof(float), stream);
    spmm_scatter_kernel<<<spmmGrid, blk, 0, stream>>>(src, dst, w, feat, bufA, nE);
    scale_kernel<<<(n4 + B - 1) / B, blk, 0, stream>>>(bufA, h, 0.5f + 0.3f, n4);

    // 5. x2 = A @ x1 ; h += 0.15 * x2
    hipMemsetAsync(bufB, 0, (size_t)nElem * sizeof(float), stream);
    spmm_scatter_kernel<<<spmmGrid, blk, 0, stream>>>(src, dst, w, bufA, bufB, nE);
    axpy_kernel<<<(n4 + B - 1) / B, blk, 0, stream>>>(bufB, h, 0.15f, n4);

    // 6. x3 = A @ x2 ; h += 0.05 * x3
    hipMemsetAsync(bufA, 0, (size_t)nElem * sizeof(float), stream);
    spmm_scatter_kernel<<<spmmGrid, blk, 0, stream>>>(src, dst, w, bufB, bufA, nE);
    axpy_kernel<<<(n4 + B - 1) / B, blk, 0, stream>>>(bufA, h, 0.05f, n4);
}

// Round 2
// 374.164 us; speedup vs baseline: 5.8124x; 5.8124x over previous
//
#include <hip/hip_runtime.h>
#include <hip/hip_bf16.h>

#define N_NODES 50000
#define N_EDGES 800000
#define D_FEAT  64

// ---------------- CSR build kernels ----------------

__global__ void hist_kernel(const int* __restrict__ src, const int* __restrict__ dst,
                            int* __restrict__ cnt_src, int* __restrict__ cnt_dst, int nE) {
    int e = blockIdx.x * blockDim.x + threadIdx.x;
    if (e < nE) {
        atomicAdd(&cnt_src[src[e]], 1);
        atomicAdd(&cnt_dst[dst[e]], 1);
    }
}

__global__ void dinv_kernel(const int* __restrict__ cnt_src, float* __restrict__ dinv, int n) {
    int i = blockIdx.x * blockDim.x + threadIdx.x;
    if (i < n) {
        int c = cnt_src[i];
        dinv[i] = (c > 0) ? rsqrtf((float)c) : 0.0f;
    }
}

// single-block exclusive scan of cnt[0..n) -> offs[0..n]
__global__ void scan_kernel(const int* __restrict__ cnt, int* __restrict__ offs, int n) {
    __shared__ int sums[1024];
    int t = threadIdx.x;
    int chunk = (n + 1023) / 1024;
    int begin = t * chunk;
    int end = min(begin + chunk, n);
    int s = 0;
    for (int i = begin; i < end; i++) s += cnt[i];
    sums[t] = s;
    __syncthreads();
    // Hillis-Steele inclusive scan
    for (int off = 1; off < 1024; off <<= 1) {
        int v = (t >= off) ? sums[t - off] : 0;
        __syncthreads();
        sums[t] += v;
        __syncthreads();
    }
    int run = (t == 0) ? 0 : sums[t - 1];
    for (int i = begin; i < end; i++) { offs[i] = run; run += cnt[i]; }
    if (end == n && begin <= n) offs[n] = run;
}

__global__ void scatter_kernel(const int* __restrict__ src, const int* __restrict__ dst,
                               const int* __restrict__ offs, int* __restrict__ cursor,
                               int* __restrict__ csr, int nE) {
    int e = blockIdx.x * blockDim.x + threadIdx.x;
    if (e < nE) {
        int d = dst[e];
        int pos = offs[d] + atomicAdd(&cursor[d], 1);
        csr[pos] = src[e];
    }
}

// ---------------- gather SpMM ----------------
// One wave per dst node; lane = feature column. No atomics.
// MODE 0: y=acc, h=theta*acc   MODE 1: y=acc, h+=theta*acc   MODE 2: h+=theta*acc (no y)
template <int MODE>
__global__ void spmm_csr_kernel(const int* __restrict__ offs, const int* __restrict__ csr,
                                const float* __restrict__ dinv,
                                const float* __restrict__ x,
                                float* __restrict__ y, float* __restrict__ h, float theta) {
    int wave = (blockIdx.x * blockDim.x + threadIdx.x) >> 6;
    int lane = threadIdx.x & 63;
    if (wave >= N_NODES) return;
    int i = wave;
    int b = offs[i], e2 = offs[i + 1];
    float acc = 0.0f;
    int j = b;
    for (; j + 4 <= e2; j += 4) {
        int s0 = csr[j], s1 = csr[j + 1], s2 = csr[j + 2], s3 = csr[j + 3];
        float w0 = dinv[s0], w1 = dinv[s1], w2 = dinv[s2], w3 = dinv[s3];
        float v0 = x[s0 * D_FEAT + lane];
        float v1 = x[s1 * D_FEAT + lane];
        float v2 = x[s2 * D_FEAT + lane];
        float v3 = x[s3 * D_FEAT + lane];
        acc += w0 * v0 + w1 * v1 + w2 * v2 + w3 * v3;
    }
    for (; j < e2; j++) {
        int s = csr[j];
        acc += dinv[s] * x[s * D_FEAT + lane];
    }
    acc *= dinv[i];
    int idx = i * D_FEAT + lane;
    if (MODE == 0)      { y[idx] = acc; h[idx] = theta * acc; }
    else if (MODE == 1) { y[idx] = acc; h[idx] += theta * acc; }
    else                { h[idx] += theta * acc; }
}

// ---------------- launch ----------------

extern "C" void kernel_launch(void* const* d_in, const int* in_sizes, int n_in,
                              void* d_out, int out_size, void* d_ws, size_t ws_size,
                              hipStream_t stream) {
    const float* feat = (const float*)d_in[0];
    const int*   src  = (const int*)d_in[1];
    const int*   dst  = (const int*)d_in[2];
    float* h = (float*)d_out;

    char* ws = (char*)d_ws;
    // layout (4B elements), 16B-aligned sections
    int*   cnt_src = (int*)(ws);                       // 50048   (reused as cursor)
    int*   cnt_dst = (int*)(ws + 50048u * 4);          // 50048
    int*   offs    = (int*)(ws + 100096u * 4);         // 50112 (need 50001)
    float* dinv    = (float*)(ws + 150208u * 4);       // 50048
    int*   csr     = (int*)(ws + 200256u * 4);         // 800000
    float* bufA    = (float*)(ws + 1000256u * 4);      // 3,200,000
    float* bufB    = (float*)(ws + 4200256u * 4);      // 3,200,000

    const int nE = N_EDGES;
    const int nN = N_NODES;
    const int B = 256;

    // 1. histograms of src (for dinv) and dst (for CSR offsets)
    hipMemsetAsync(cnt_src, 0, (size_t)nN * sizeof(int), stream);
    hipMemsetAsync(cnt_dst, 0, (size_t)nN * sizeof(int), stream);
    hist_kernel<<<(nE + B - 1) / B, B, 0, stream>>>(src, dst, cnt_src, cnt_dst, nE);

    // 2. dinv = rsqrt(deg_src)
    dinv_kernel<<<(nN + B - 1) / B, B, 0, stream>>>(cnt_src, dinv, nN);

    // 3. exclusive scan of cnt_dst -> offs
    scan_kernel<<<1, 1024, 0, stream>>>(cnt_dst, offs, nN);

    // 4. scatter edges into CSR (cursor reuses cnt_src storage)
    hipMemsetAsync(cnt_src, 0, (size_t)nN * sizeof(int), stream);
    scatter_kernel<<<(nE + B - 1) / B, B, 0, stream>>>(src, dst, offs, cnt_src, csr, nE);

    // 5. three gather SpMMs, combine fused into epilogue
    const int spmmGrid = (nN * 64 + B - 1) / B;   // one wave per node
    spmm_csr_kernel<0><<<spmmGrid, B, 0, stream>>>(offs, csr, dinv, feat, bufA, h, 0.5f + 0.3f);
    spmm_csr_kernel<1><<<spmmGrid, B, 0, stream>>>(offs, csr, dinv, bufA, bufB, h, 0.15f);
    spmm_csr_kernel<2><<<spmmGrid, B, 0, stream>>>(offs, csr, dinv, bufB, nullptr, h, 0.05f);
}

// Round 4
// 298.027 us; speedup vs baseline: 7.2973x; 1.2555x over previous
//
#include <hip/hip_runtime.h>
#include <hip/hip_bf16.h>

#define N_NODES 50000
#define N_EDGES 800000
#define D_FEAT  64
#define SCAN_B  256
#define SCAN_NBLK ((N_NODES + SCAN_B - 1) / SCAN_B)   // 196

// ---------------- CSR build kernels ----------------

__global__ void hist_kernel(const int* __restrict__ src, const int* __restrict__ dst,
                            int* __restrict__ cnt_src, int* __restrict__ cnt_dst, int nE) {
    int e = blockIdx.x * blockDim.x + threadIdx.x;
    if (e < nE) {
        atomicAdd(&cnt_src[src[e]], 1);
        atomicAdd(&cnt_dst[dst[e]], 1);
    }
}

// Phase A: per-block sums of cnt_dst -> partials; fused dinv = rsqrt(cnt_src)
__global__ void scanA_kernel(const int* __restrict__ cnt_dst, int* __restrict__ partials,
                             const int* __restrict__ cnt_src, float* __restrict__ dinv, int n) {
    __shared__ int red[SCAN_B];
    int t = threadIdx.x;
    int idx = blockIdx.x * SCAN_B + t;
    int v = (idx < n) ? cnt_dst[idx] : 0;
    if (idx < n) {
        int c = cnt_src[idx];
        dinv[idx] = (c > 0) ? rsqrtf((float)c) : 0.0f;
    }
    red[t] = v;
    __syncthreads();
    for (int off = SCAN_B / 2; off > 0; off >>= 1) {
        if (t < off) red[t] += red[t + off];
        __syncthreads();
    }
    if (t == 0) partials[blockIdx.x] = red[0];
}

// Phase B: single block scans NBLK partials -> exclusive blockbase; writes offs[n]=total
__global__ void scanB_kernel(const int* __restrict__ partials, int* __restrict__ blockbase,
                             int* __restrict__ offs, int n) {
    __shared__ int s[SCAN_B];
    int t = threadIdx.x;
    int v = (t < SCAN_NBLK) ? partials[t] : 0;
    s[t] = v;
    __syncthreads();
    // Hillis-Steele inclusive
    for (int off = 1; off < SCAN_B; off <<= 1) {
        int u = (t >= off) ? s[t - off] : 0;
        __syncthreads();
        s[t] += u;
        __syncthreads();
    }
    if (t < SCAN_NBLK) blockbase[t] = (t == 0) ? 0 : s[t - 1];
    if (t == SCAN_NBLK - 1) offs[n] = s[t];
}

// Phase C: per-block exclusive scan of cnt_dst + blockbase -> offs
__global__ void scanC_kernel(const int* __restrict__ cnt_dst, const int* __restrict__ blockbase,
                             int* __restrict__ offs, int n) {
    __shared__ int s[SCAN_B];
    int t = threadIdx.x;
    int idx = blockIdx.x * SCAN_B + t;
    int v = (idx < n) ? cnt_dst[idx] : 0;
    s[t] = v;
    __syncthreads();
    for (int off = 1; off < SCAN_B; off <<= 1) {
        int u = (t >= off) ? s[t - off] : 0;
        __syncthreads();
        s[t] += u;
        __syncthreads();
    }
    if (idx < n) offs[idx] = blockbase[blockIdx.x] + s[t] - v;   // exclusive
}

__global__ void scatter_kernel(const int* __restrict__ src, const int* __restrict__ dst,
                               const int* __restrict__ offs, int* __restrict__ cursor,
                               int* __restrict__ csr, int nE) {
    int e = blockIdx.x * blockDim.x + threadIdx.x;
    if (e < nE) {
        int d = dst[e];
        int pos = offs[d] + atomicAdd(&cursor[d], 1);
        csr[pos] = src[e];
    }
}

// ---------------- gather SpMM ----------------
// One wave per dst node; lane = feature column. No atomics.
// MODE 0: y=acc, h=theta*acc   MODE 1: y=acc, h+=theta*acc   MODE 2: h+=theta*acc (no y)
template <int MODE>
__global__ void spmm_csr_kernel(const int* __restrict__ offs, const int* __restrict__ csr,
                                const float* __restrict__ dinv,
                                const float* __restrict__ x,
                                float* __restrict__ y, float* __restrict__ h, float theta) {
    int wave = (blockIdx.x * blockDim.x + threadIdx.x) >> 6;
    int lane = threadIdx.x & 63;
    if (wave >= N_NODES) return;
    int i = wave;
    int b = offs[i], e2 = offs[i + 1];
    float acc = 0.0f;
    int j = b;
    for (; j + 4 <= e2; j += 4) {
        int s0 = csr[j], s1 = csr[j + 1], s2 = csr[j + 2], s3 = csr[j + 3];
        float w0 = dinv[s0], w1 = dinv[s1], w2 = dinv[s2], w3 = dinv[s3];
        float v0 = x[s0 * D_FEAT + lane];
        float v1 = x[s1 * D_FEAT + lane];
        float v2 = x[s2 * D_FEAT + lane];
        float v3 = x[s3 * D_FEAT + lane];
        acc += w0 * v0 + w1 * v1 + w2 * v2 + w3 * v3;
    }
    for (; j < e2; j++) {
        int s = csr[j];
        acc += dinv[s] * x[s * D_FEAT + lane];
    }
    acc *= dinv[i];
    int idx = i * D_FEAT + lane;
    if (MODE == 0)      { y[idx] = acc; h[idx] = theta * acc; }
    else if (MODE == 1) { y[idx] = acc; h[idx] += theta * acc; }
    else                { h[idx] += theta * acc; }
}

// ---------------- launch ----------------

extern "C" void kernel_launch(void* const* d_in, const int* in_sizes, int n_in,
                              void* d_out, int out_size, void* d_ws, size_t ws_size,
                              hipStream_t stream) {
    const float* feat = (const float*)d_in[0];
    const int*   src  = (const int*)d_in[1];
    const int*   dst  = (const int*)d_in[2];
    float* h = (float*)d_out;

    char* ws = (char*)d_ws;
    // layout (4B elements), 16B-aligned sections. cnt_src|cnt_dst|cursor contiguous (one memset).
    int*   cnt_src  = (int*)(ws);                       // 50048
    int*   cnt_dst  = (int*)(ws + 50048u * 4);          // 50048
    int*   cursor   = (int*)(ws + 100096u * 4);         // 50048
    int*   offs     = (int*)(ws + 150144u * 4);         // 50112 (need 50001)
    float* dinv     = (float*)(ws + 200256u * 4);       // 50048
    int*   partials = (int*)(ws + 250304u * 4);         // 256
    int*   blockbase= (int*)(ws + 250560u * 4);         // 256
    int*   csr      = (int*)(ws + 250816u * 4);         // 800000
    float* bufA     = (float*)(ws + 1050816u * 4);      // 3,200,000
    float* bufB     = (float*)(ws + 4250816u * 4);      // 3,200,000

    const int nE = N_EDGES;
    const int nN = N_NODES;
    const int B = 256;

    // 1. zero all three counter arrays in one memset
    hipMemsetAsync(cnt_src, 0, (size_t)(3 * 50048) * sizeof(int), stream);
    hist_kernel<<<(nE + B - 1) / B, B, 0, stream>>>(src, dst, cnt_src, cnt_dst, nE);

    // 2. parallel exclusive scan of cnt_dst -> offs (dinv fused into phase A)
    scanA_kernel<<<SCAN_NBLK, SCAN_B, 0, stream>>>(cnt_dst, partials, cnt_src, dinv, nN);
    scanB_kernel<<<1, SCAN_B, 0, stream>>>(partials, blockbase, offs, nN);
    scanC_kernel<<<SCAN_NBLK, SCAN_B, 0, stream>>>(cnt_dst, blockbase, offs, nN);

    // 3. scatter edges into CSR
    scatter_kernel<<<(nE + B - 1) / B, B, 0, stream>>>(src, dst, offs, cursor, csr, nE);

    // 4. three gather SpMMs, combine fused into epilogue
    const int spmmGrid = (nN * 64 + B - 1) / B;   // one wave per node
    spmm_csr_kernel<0><<<spmmGrid, B, 0, stream>>>(offs, csr, dinv, feat, bufA, h, 0.5f + 0.3f);
    spmm_csr_kernel<1><<<spmmGrid, B, 0, stream>>>(offs, csr, dinv, bufA, bufB, h, 0.15f);
    spmm_csr_kernel<2><<<spmmGrid, B, 0, stream>>>(offs, csr, dinv, bufB, nullptr, h, 0.05f);
}